// Round 19
// baseline (243.532 us; speedup 1.0000x reference)
//
#include <hip/hip_runtime.h>
#include <cstdint>
#include <cstddef>

typedef _Float16 f16;
typedef _Float16 f16x8 __attribute__((ext_vector_type(8)));
typedef _Float16 f16x4 __attribute__((ext_vector_type(4)));
typedef float    f32x4 __attribute__((ext_vector_type(4)));
typedef float    f32x16 __attribute__((ext_vector_type(16)));
typedef int      i32x4 __attribute__((ext_vector_type(4)));

#define S_CTX 2048
#define NH 16
#define DH 128

#define BAR() asm volatile("s_barrier" ::: "memory")
#define VMW(n) asm volatile("s_waitcnt vmcnt(" #n ")" ::: "memory")
#define MF(a, b, c) __builtin_amdgcn_mfma_f32_16x16x32_f16((a), (b), (c), 0, 0, 0)
#define MF32(a, b, c) __builtin_amdgcn_mfma_f32_32x32x16_f16((a), (b), (c), 0, 0, 0)

__device__ __forceinline__ void gload16(const void* g, void* l) {
  __builtin_amdgcn_global_load_lds(
      (const __attribute__((address_space(1))) void*)g,
      (__attribute__((address_space(3))) void*)l, 16, 0, 0);
}

__device__ __forceinline__ int pk2(float a, float b) {
  auto hv = __builtin_amdgcn_cvt_pkrtz(a, b);
  return __builtin_bit_cast(int, hv);
}
// v_permlane32_swap_b32: vdst[32:63] <-> vsrc[0:31]
__device__ __forceinline__ void pl_swap(int& a, int& b) {
  asm volatile("v_permlane32_swap_b32 %0, %1" : "+v"(a), "+v"(b));
}

// ---------- prep: rope tables + x->f16 + 4x weight transpose, one dispatch ----------
__global__ void prep(const float* __restrict__ x,
                     const float* __restrict__ w0, const float* __restrict__ w1,
                     const float* __restrict__ w2, const float* __restrict__ w3,
                     f16* __restrict__ xb,
                     f16* __restrict__ o0, f16* __restrict__ o1,
                     f16* __restrict__ o2, f16* __restrict__ o3,
                     float* __restrict__ sint, float* __restrict__ cost) {
  const int bid = blockIdx.x, tid = threadIdx.x;
  if (bid < 512) {                       // rope tables: 2048*64
    int idx = bid * 256 + tid;
    int j = idx & 63, s = idx >> 6;
    float invf = __expf(-(float)(2 * j) * (1.0f / 128.0f) * 9.210340371976184f);
    float a = (float)s * invf;
    sint[idx] = sinf(a);
    cost[idx] = cosf(a);
  } else if (bid < 8704) {               // x fp32 -> fp16
    int i = ((bid - 512) * 256 + tid) * 4;
    float4 v = *(const float4*)(x + i);
    f16x4 o; o[0] = (f16)v.x; o[1] = (f16)v.y; o[2] = (f16)v.z; o[3] = (f16)v.w;
    *(f16x4*)(xb + i) = o;
  } else {                               // W[k][n] fp32 -> Wt[n][k] fp16
    int b2 = bid - 8704;
    int z = b2 >> 12, rem = b2 & 4095;
    int by = rem >> 6, bx = rem & 63;
    int tx = tid & 31, ty = tid >> 5;
    const float* in; f16* out;
    switch (z) {
      case 0: in = w0; out = o0; break;
      case 1: in = w1; out = o1; break;
      case 2: in = w2; out = o2; break;
      default: in = w3; out = o3; break;
    }
    __shared__ float tl[32][33];
    int xc = bx * 32 + tx, yc = by * 32 + ty;
#pragma unroll
    for (int r = 0; r < 32; r += 8)
      tl[ty + r][tx] = in[(size_t)(yc + r) * 2048 + xc];
    __syncthreads();
    int xo = by * 32 + tx, yo = bx * 32 + ty;
#pragma unroll
    for (int r = 0; r < 32; r += 8)
      out[(size_t)(yo + r) * 2048 + xo] = (f16)tl[tx][ty + r];
  }
}

// ---------- Q+K fused GEMM (R4-proven fine-phase body, 1-round grid) ----------
// 256^2 tile, 8 waves (2M x 4N), per-wave 128x64. K in 64 halves of 32.
// Phase = half-M-quadrant x all-N x K=32: 4 af reads (+4 bf cached at mh=0),
// 16 MFMA per barrier-pair; stage ONE A- or B-pair (2 loads) per phase;
// VMW(8) at odd phases (never 0 mid-loop). LDS: A slots 0..64K, B 64K..128K.
// R4 measured per-round latency 64.3us (=1067 TF) vs R13-structure 73.5 (935).
// grid (16,16) = 256 blocks = exactly 1 round. proj = gcol>>11 (0=Q,1=K).
__global__ __launch_bounds__(512, 1)
void gemm_qk(const f16* __restrict__ A, const f16* __restrict__ wqT,
             const f16* __restrict__ wkT,
             f16* __restrict__ qb, f16* __restrict__ kb,
             const float* __restrict__ sint, const float* __restrict__ cost) {
  extern __shared__ __align__(16) char lds[];
#define RING_A(e) (lds + (e) * 16384)
#define RING_B(e) (lds + 65536 + (e) * 16384)
  const int tid = threadIdx.x, lane = tid & 63;
  const int wvi = tid >> 6, wm = wvi >> 2, wn = wvi & 3;
  const int gcol = blockIdx.x * 256;
  const int proj = gcol >> 11;           // 0 = Q, 1 = K
  const int col0 = gcol & 2047;
  const int row0 = blockIdx.y * 256;
  const f16* Bt = proj ? wkT : wqT;

  const int ca0 = tid, ca1 = tid + 512;
  const int ra0 = ca0 >> 2, ra1 = ca1 >> 2;
  const int sa0 = (ca0 & 3) ^ ((ra0 >> 1) & 3);
  const int sa1 = (ca1 & 3) ^ ((ra1 >> 1) & 3);
  const f16* gA0 = A + (size_t)(row0 + ra0) * 2048 + sa0 * 8;
  const f16* gA1 = A + (size_t)(row0 + ra1) * 2048 + sa1 * 8;
  const f16* gB0 = Bt + (size_t)(col0 + ra0) * 2048 + sa0 * 8;
  const f16* gB1 = Bt + (size_t)(col0 + ra1) * 2048 + sa1 * 8;

  const int kslot = lane >> 4;
  int aoff[8], boff[4];
#pragma unroll
  for (int i = 0; i < 8; i++) {
    int row = wm * 128 + i * 16 + (lane & 15);
    aoff[i] = row * 64 + ((kslot ^ ((row >> 1) & 3)) << 4);
  }
#pragma unroll
  for (int j = 0; j < 4; j++) {
    int rb = (wn >> 1) * 128 + (wn & 1) * 32 + (j & 1) * 16 + (j >> 1) * 64 + (lane & 15);
    boff[j] = rb * 64 + ((kslot ^ ((rb >> 1) & 3)) << 4);
  }

  f32x4 acc[8][4] = {};
  f16x8 bfc[4];

  // phase: ds-reads (bf cached at mh==0) | stage one pair | BARRIER | 16 MFMA
  auto PH = [&](int e, int mh, int stagemat, int h) {
    const char* As_ = RING_A(e);
    const char* Bs_ = RING_B(e);
    f16x8 af[4];
#pragma unroll
    for (int ii = 0; ii < 4; ii++)
      af[ii] = *(const f16x8*)(As_ + aoff[mh * 4 + ii]);
    if (mh == 0) {
#pragma unroll
      for (int j = 0; j < 4; j++)
        bfc[j] = *(const f16x8*)(Bs_ + boff[j]);
    }
    if (stagemat == 0) {
      gload16(gA0 + h * 32, RING_A(h & 3) + ca0 * 16);
      gload16(gA1 + h * 32, RING_A(h & 3) + ca1 * 16);
    } else if (stagemat == 1) {
      gload16(gB0 + h * 32, RING_B(h & 3) + ca0 * 16);
      gload16(gB1 + h * 32, RING_B(h & 3) + ca1 * 16);
    }
    BAR();
    __builtin_amdgcn_s_setprio(1);
#pragma unroll
    for (int j = 0; j < 4; j++)
#pragma unroll
      for (int ii = 0; ii < 4; ii++)
        acc[mh * 4 + ii][j] = MF(af[ii], bfc[j], acc[mh * 4 + ii][j]);
    __builtin_amdgcn_s_setprio(0);
  };

  // prologue: stage halves 0,1,2 (A+B pairs, 12 loads); VMW(8) proves half 0
#pragma unroll
  for (int h = 0; h < 3; h++) {
    gload16(gA0 + h * 32, RING_A(h) + ca0 * 16);
    gload16(gA1 + h * 32, RING_A(h) + ca1 * 16);
    gload16(gB0 + h * 32, RING_B(h) + ca0 * 16);
    gload16(gB1 + h * 32, RING_B(h) + ca1 * 16);
  }
  VMW(8); BAR();

  for (int t = 0; t < 30; ++t) {
    int e0 = (2 * t) & 3, e1 = (2 * t + 1) & 3;
    PH(e0, 0, 0, 2 * t + 3);          BAR();
    PH(e0, 1, 1, 2 * t + 3); VMW(8);  BAR();
    PH(e1, 0, 0, 2 * t + 4);          BAR();
    PH(e1, 1, 1, 2 * t + 4); VMW(8);  BAR();
  }
  // tail: halves 60..63; stage only half 63
  PH(0, 0, 0, 63);          BAR();
  PH(0, 1, 1, 63); VMW(8);  BAR();
  PH(1, 0, 2, 0);           BAR();
  PH(1, 1, 2, 0);  VMW(4);  BAR();
  PH(2, 0, 2, 0);           BAR();
  PH(2, 1, 2, 0);  VMW(0);  BAR();
  PH(3, 0, 2, 0);           BAR();
  PH(3, 1, 2, 0);           BAR();

  // RoPE epilogue
  const int b = row0 >> 11, sb = row0 & 2047;
  f16* dst = proj ? kb : qb;
  const int h = (col0 >> 7) + (wn >> 1);
#pragma unroll
  for (int i = 0; i < 8; i++)
#pragma unroll
    for (int jj = 0; jj < 2; jj++)
#pragma unroll
      for (int r = 0; r < 4; r++) {
        int s = sb + wm * 128 + i * 16 + (lane >> 4) * 4 + r;
        int d = (wn & 1) * 32 + jj * 16 + (lane & 15);
        float cv = cost[s * 64 + d], sv = sint[s * 64 + d];
        float x1 = acc[i][jj][r], x2 = acc[i][jj + 2][r];
        size_t base = ((size_t)(b * NH + h) * S_CTX + s) << 7;
        dst[base + d]      = (f16)(x1 * cv - x2 * sv);
        dst[base + d + 64] = (f16)(x2 * cv + x1 * sv);
      }
#undef RING_A
#undef RING_B
}

// ---------- 8-phase GEMM (R13-proven): tile 256x128; MODE 1 = V^T epi, 2 = f32 epi ----------
template<int MODE>
__global__ __launch_bounds__(512, 1)
void gemm8(const f16* __restrict__ A, const f16* __restrict__ Bt,
           f16* __restrict__ vtb, float* __restrict__ of) {
  extern __shared__ __align__(16) char lds[];
#define RING_A(e) (lds + (e) * 16384)
#define RING_B(e) (lds + 65536 + (e) * 8192)
  const int tid = threadIdx.x, lane = tid & 63;
  const int wvi = tid >> 6, wm = wvi >> 1, wn = wvi & 1;
  const int col0 = blockIdx.x * 128;
  const int row0 = blockIdx.y * 256;

  const int ca0 = tid, ca1 = tid + 512, cb0 = tid;
  const int rAs0 = ca0 >> 2, rAs1 = ca1 >> 2, rBs0 = cb0 >> 2;
  const int sA0 = (ca0 & 3) ^ ((rAs0 >> 1) & 3);
  const int sA1 = (ca1 & 3) ^ ((rAs1 >> 1) & 3);
  const int sB0 = (cb0 & 3) ^ ((rBs0 >> 1) & 3);
  const f16* gA0 = A + (size_t)(row0 + rAs0) * 2048 + sA0 * 8;
  const f16* gA1 = A + (size_t)(row0 + rAs1) * 2048 + sA1 * 8;
  const f16* gB0 = Bt + (size_t)(col0 + rBs0) * 2048 + sB0 * 8;

  const int kslot = lane >> 4;
  int aoff[4], boff[4];
#pragma unroll
  for (int i = 0; i < 4; i++) {
    int row = wm * 64 + i * 16 + (lane & 15);
    aoff[i] = row * 64 + ((kslot ^ ((row >> 1) & 3)) << 4);
  }
#pragma unroll
  for (int j = 0; j < 4; j++) {
    int rb = wn * 32 + (j & 1) * 16 + (j >> 1) * 64 + (lane & 15);
    boff[j] = rb * 64 + ((kslot ^ ((rb >> 1) & 3)) << 4);
  }

  f32x4 acc[4][4] = {};

#define PH8(SLOT, HS, DOSTAGE, WN) do {                                        \
    const char* As_ = RING_A(SLOT);                                            \
    const char* Bs_ = RING_B(SLOT);                                            \
    f16x8 af[4], bf[4];                                                        \
    _Pragma("unroll") for (int i_ = 0; i_ < 4; i_++)                           \
      af[i_] = *(const f16x8*)(As_ + aoff[i_]);                                \
    _Pragma("unroll") for (int j_ = 0; j_ < 4; j_++)                           \
      bf[j_] = *(const f16x8*)(Bs_ + boff[j_]);                                \
    if (DOSTAGE) {                                                             \
      gload16(gA0 + (HS) * 32, RING_A((HS) & 3) + ca0 * 16);                   \
      gload16(gA1 + (HS) * 32, RING_A((HS) & 3) + ca1 * 16);                   \
      gload16(gB0 + (HS) * 32, RING_B((HS) & 3) + cb0 * 16);                   \
    }                                                                          \
    asm volatile("s_waitcnt vmcnt(" #WN ")" ::: "memory");                     \
    BAR();                                                                     \
    __builtin_amdgcn_s_setprio(1);                                             \
    _Pragma("unroll") for (int i_ = 0; i_ < 4; i_++)                           \
      _Pragma("unroll") for (int j_ = 0; j_ < 4; j_++)                         \
        acc[i_][j_] = MF(af[i_], bf[j_], acc[i_][j_]);                         \
    __builtin_amdgcn_s_setprio(0);                                             \
    BAR();                                                                     \
  } while (0)

#pragma unroll
  for (int h = 0; h < 3; h++) {
    gload16(gA0 + h * 32, RING_A(h) + ca0 * 16);
    gload16(gA1 + h * 32, RING_A(h) + ca1 * 16);
    gload16(gB0 + h * 32, RING_B(h) + cb0 * 16);
  }
  VMW(6); BAR();

  for (int t = 0; t < 15; ++t) {
    const int p = t * 4;
    PH8(0, p + 3, 1, 6);
    PH8(1, p + 4, 1, 6);
    PH8(2, p + 5, 1, 6);
    PH8(3, p + 6, 1, 6);
  }
  PH8(0, 63, 1, 6);
  PH8(1, 0, 0, 3);
  PH8(2, 0, 0, 0);
  PH8(3, 0, 0, 63);
#undef PH8

  const int b = row0 >> 11, sbase = row0 & 2047;

  if (MODE == 2) {
#pragma unroll
    for (int i = 0; i < 4; i++)
#pragma unroll
      for (int j = 0; j < 4; j++)
#pragma unroll
        for (int r = 0; r < 4; r++) {
          int row = row0 + wm * 64 + i * 16 + (lane >> 4) * 4 + r;
          int col = col0 + wn * 32 + (j & 1) * 16 + (j >> 1) * 64 + (lane & 15);
          of[(size_t)row * 2048 + col] = acc[i][j][r];
        }
  } else {
    // V^T epilogue: [256 s][128 d] -> vtb[b,h,d,s] via LDS (f16x4 units, XOR swz)
    const int h = col0 >> 7;
    f16x4* ldsv = (f16x4*)lds;
#pragma unroll
    for (int i = 0; i < 4; i++)
#pragma unroll
      for (int j = 0; j < 4; j++) {
        f16x4 v;
#pragma unroll
        for (int r = 0; r < 4; r++) v[r] = (f16)acc[i][j][r];
        int su = wm * 16 + i * 4 + (lane >> 4);
        int d  = wn * 32 + (j & 1) * 16 + (j >> 1) * 64 + (lane & 15);
        ldsv[d * 64 + (su ^ ((d << 1) & 63))] = v;
      }
    __syncthreads();
#pragma unroll
    for (int it = 0; it < 8; ++it) {
      int o = it * 512 + tid;
      int d = o >> 5, c = o & 31;
      int xc = (d << 1) & 63;
      f16x4 lo = ldsv[d * 64 + ((2 * c) ^ xc)];
      f16x4 hi = ldsv[d * 64 + ((2 * c + 1) ^ xc)];
      f16x8 vv;
      vv[0] = lo[0]; vv[1] = lo[1]; vv[2] = lo[2]; vv[3] = lo[3];
      vv[4] = hi[0]; vv[5] = hi[1]; vv[6] = hi[2]; vv[7] = hi[3];
      *(f16x8*)&vtb[((size_t)(b * NH + h) * DH + d) * S_CTX + sbase + c * 8] = vv;
    }
  }
#undef RING_A
#undef RING_B
}

// ---------- flash attention v5 (R15-proven): DUAL-STREAM, two independent 4-wave halves ----------
__global__ __launch_bounds__(512, 1)
void attn_k(const f16* __restrict__ q, const f16* __restrict__ kk,
            const f16* __restrict__ vt, f16* __restrict__ ctx) {
  extern __shared__ __align__(16) char alds[];
  const int tid = threadIdx.x, lane = tid & 63;
  const int halfid = tid >> 8;            // 0 = half A, 1 = half B
  const int tid2 = tid & 255;
  const int wv2 = tid2 >> 6;              // wave within half, 0..3
  const int lh = lane >> 5, q31 = lane & 31;
  const int bid = blockIdx.x;
  const int bh = (bid & 7) + 8 * ((bid >> 3) & 3);
  const int idxQ = bid >> 5;              // 0..7
  const int b = bh >> 4, h = bh & 15;
  const size_t plane = (size_t)bh * (S_CTX * DH);
  const f16* Qp = q + plane;
  const f16* Kp = kk + plane;
  const f16* Vp = vt + plane;
  const float LOG2E = 1.4426950408889634f;

  char* myH = alds + halfid * 65536;      // this half's 64KB K/V region
  float* O_lds = (float*)(alds + 65536);  // merge buffer = half B's region (dead K/V)
  float* ml_lds = (float*)alds;           // merge m/l = half A's region start

#define STAGE(T, BUF) do {                                                      \
    const f16* Kt = Kp + (size_t)(T) * 64 * DH;                                 \
    const f16* Vt = Vp + (size_t)(T) * 64;                                      \
    char* kb_ = myH + (BUF) * 16384;                                            \
    char* vb_ = myH + 32768 + (BUF) * 16384;                                    \
    _Pragma("unroll") for (int j_ = 0; j_ < 4; j_++) {                          \
      int c = tid2 + j_ * 256; int rk = c >> 4;                                 \
      gload16(Kt + (size_t)rk * DH + (((c & 15) ^ (rk & 7)) * 8), kb_ + c * 16); \
    }                                                                           \
    _Pragma("unroll") for (int j_ = 0; j_ < 4; j_++) {                          \
      int c = tid2 + j_ * 256; int rv = c >> 3;                                 \
      gload16(Vt + (size_t)rv * S_CTX + (((c & 7) ^ (rv & 7)) * 8), vb_ + c * 16); \
    }                                                                           \
  } while (0)

  for (int p = 0; p < 2; ++p) {
    const int Qt = p ? (15 - idxQ) : idxQ;
    const int q0 = Qt * 128;
    const int NTh = Qt + 1;               // iters per half (NT = 2Qt+2 split even/odd)

    // Q fragments (B-operand): lane holds Q[q0+wv2*32+q31][d = 16s + 8*lh + e]
    f16x8 qf[8];
    {
      const f16* qq = Qp + (size_t)(q0 + wv2 * 32 + q31) * DH + lh * 8;
#pragma unroll
      for (int s = 0; s < 8; s++) {
        qf[s] = *(const f16x8*)(qq + s * 16);
#pragma unroll
        for (int e = 0; e < 8; e++) qf[s][e] = (f16)((float)qf[s][e] * LOG2E);
      }
    }
    float m_ = -3e38f, l_ = 0.f;
    f32x16 o[4] = {};

    STAGE(halfid, 0);
    VMW(0); BAR();

    int cur = 0;
    for (int i = 0; i < NTh; i++) {
      const int t = 2 * i + halfid;
      if (i + 1 < NTh) STAGE(2 * (i + 1) + halfid, cur ^ 1);
      const f16* Ksc = (const f16*)(myH + cur * 16384);
      const f16* Vsc = (const f16*)(myH + 32768 + cur * 16384);

      // S^T = K Q (log2 units)
      f32x16 st0 = {}, st1 = {};
      __builtin_amdgcn_s_setprio(1);
#pragma unroll
      for (int s = 0; s < 8; s++) {
        const int r0 = q31, r1 = 32 + q31;
        f16x8 kf0 = *(const f16x8*)&Ksc[r0 * 128 + (((2 * s + lh) ^ (r0 & 7)) << 3)];
        f16x8 kf1 = *(const f16x8*)&Ksc[r1 * 128 + (((2 * s + lh) ^ (r1 & 7)) << 3)];
        st0 = MF32(kf0, qf[s], st0);
        st1 = MF32(kf1, qf[s], st1);
      }
      __builtin_amdgcn_s_setprio(0);

      // causal mask (diagonal band: t in {2Qt, 2Qt+1})
      if (t >= 2 * Qt) {
        const int qg = q0 + wv2 * 32 + q31;
#pragma unroll
        for (int r = 0; r < 16; r++) {
          int kvb = t * 64 + (r & 3) + 8 * (r >> 2) + 4 * lh;
          if (kvb > qg) st0[r] = -3e38f;
          if (kvb + 32 > qg) st1[r] = -3e38f;
        }
      }
      // row max: in-lane + partner half-lane
      float mx = st0[0];
#pragma unroll
      for (int r = 1; r < 16; r++) mx = fmaxf(mx, st0[r]);
#pragma unroll
      for (int r = 0; r < 16; r++) mx = fmaxf(mx, st1[r]);
      mx = fmaxf(mx, __shfl_xor(mx, 32));
      if (__any(mx > m_ + 8.0f)) {
        float nm = fmaxf(m_, mx);
        float al = __builtin_amdgcn_exp2f(m_ - nm);
        m_ = nm; l_ *= al;
#pragma unroll
        for (int r = 0; r < 16; r++) {
          float alr = __shfl(al, (r & 3) + 8 * (r >> 2) + 4 * lh);
#pragma unroll
          for (int j = 0; j < 4; j++) o[j][r] *= alr;
        }
      }
      float s_ = 0.f;
#pragma unroll
      for (int r = 0; r < 16; r++) { st0[r] = __builtin_amdgcn_exp2f(st0[r] - m_); s_ += st0[r]; }
#pragma unroll
      for (int r = 0; r < 16; r++) { st1[r] = __builtin_amdgcn_exp2f(st1[r] - m_); s_ += st1[r]; }
      s_ += __shfl_xor(s_, 32);
      l_ += s_;

      // pack P -> A-frags (16 cvt_pk + 8 permlane32_swap)
      f16x8 pa[4];
      {
        int w0 = pk2(st0[0], st0[1]),   w1 = pk2(st0[2], st0[3]);
        int w2 = pk2(st0[4], st0[5]),   w3 = pk2(st0[6], st0[7]);
        int w4 = pk2(st0[8], st0[9]),   w5 = pk2(st0[10], st0[11]);
        int w6 = pk2(st0[12], st0[13]), w7 = pk2(st0[14], st0[15]);
        pl_swap(w0, w2); pl_swap(w1, w3); pl_swap(w4, w6); pl_swap(w5, w7);
        i32x4 a = {w0, w1, w2, w3}; pa[0] = __builtin_bit_cast(f16x8, a);
        i32x4 bb = {w4, w5, w6, w7}; pa[1] = __builtin_bit_cast(f16x8, bb);
      }
      {
        int w0 = pk2(st1[0], st1[1]),   w1 = pk2(st1[2], st1[3]);
        int w2 = pk2(st1[4], st1[5]),   w3 = pk2(st1[6], st1[7]);
        int w4 = pk2(st1[8], st1[9]),   w5 = pk2(st1[10], st1[11]);
        int w6 = pk2(st1[12], st1[13]), w7 = pk2(st1[14], st1[15]);
        pl_swap(w0, w2); pl_swap(w1, w3); pl_swap(w4, w6); pl_swap(w5, w7);
        i32x4 a = {w0, w1, w2, w3}; pa[2] = __builtin_bit_cast(f16x8, a);
        i32x4 bb = {w4, w5, w6, w7}; pa[3] = __builtin_bit_cast(f16x8, bb);
      }

      // O += P V
      __builtin_amdgcn_s_setprio(1);
#pragma unroll
      for (int j = 0; j < 4; j++) {
        const int rv = 32 * j + q31;
#pragma unroll
        for (int s2 = 0; s2 < 4; s2++) {
          f16x8 vf = *(const f16x8*)&Vsc[rv * 64 + (((2 * s2 + lh) ^ (rv & 7)) << 3)];
          o[j] = MF32(pa[s2], vf, o[j]);
        }
      }
      __builtin_amdgcn_s_setprio(0);

      VMW(0); BAR();
      cur ^= 1;
    }

    // ---- merge: B spills, A combines + writes ctx ----
    if (halfid) {
      ml_lds[(wv2 * 32 + q31) * 2]     = m_;
      ml_lds[(wv2 * 32 + q31) * 2 + 1] = l_;
#pragma unroll
      for (int r = 0; r < 16; r++) {
        int crow = (r & 3) + 8 * (r >> 2) + 4 * lh;
#pragma unroll
        for (int j = 0; j < 4; j++)
          O_lds[(wv2 * 32 + crow) * 128 + 32 * j + q31] = o[j][r];
      }
    }
    BAR();
    if (!halfid) {
      float mB = ml_lds[(wv2 * 32 + q31) * 2];
      float lB = ml_lds[(wv2 * 32 + q31) * 2 + 1];
      float m = fmaxf(m_, mB);
      float aA = __builtin_amdgcn_exp2f(m_ - m);
      float aB = __builtin_amdgcn_exp2f(mB - m);
      float lfin = l_ * aA + lB * aB;
      float inv = 1.0f / lfin;
#pragma unroll
      for (int r = 0; r < 16; r++) {
        int crow = (r & 3) + 8 * (r >> 2) + 4 * lh;
        float aAr = __shfl(aA, crow);
        float aBr = __shfl(aB, crow);
        float invr = __shfl(inv, crow);
        int qg = q0 + wv2 * 32 + crow;
#pragma unroll
        for (int j = 0; j < 4; j++) {
          float ov = o[j][r] * aAr + O_lds[(wv2 * 32 + crow) * 128 + 32 * j + q31] * aBr;
          ctx[((size_t)(b * S_CTX + qg) * 2048) + h * 128 + 32 * j + q31] = (f16)(ov * invr);
        }
      }
    }
    BAR();   // O_lds / ml_lds regions reused as K/V next tile
  }
#undef STAGE
}

extern "C" void kernel_launch(void* const* d_in, const int* in_sizes, int n_in,
                              void* d_out, int out_size, void* d_ws, size_t ws_size,
                              hipStream_t stream) {
  (void)in_sizes; (void)n_in; (void)out_size; (void)ws_size;
  const float* x  = (const float*)d_in[0];
  const float* Wq = (const float*)d_in[1];
  const float* Wk = (const float*)d_in[2];
  const float* Wv = (const float*)d_in[3];
  const float* Wo = (const float*)d_in[4];
  float* out = (float*)d_out;
  char* ws = (char*)d_ws;

  f16*   xb   = (f16*)(ws);                    // x fp16 [4096][2048]
  f16*   ctxb = (f16*)(ws);                    // reuse (xb dead after QKV)
  f16*   wqT  = (f16*)(ws + 16777216);         // [n][k] fp16, 8 MB each
  f16*   wkT  = (f16*)(ws + 25165824);
  f16*   wvT  = (f16*)(ws + 33554432);
  f16*   woT  = (f16*)(ws + 41943040);
  f16*   qb   = (f16*)(ws + 50331648);         // [b,h,s,d] fp16 (rope applied)
  f16*   kb   = (f16*)(ws + 67108864);
  f16*   vtb  = (f16*)(ws + 83886080);         // [b,h,d,s] fp16
  float* sint = (float*)(ws + 100663296);      // [2048][64]
  float* cost = (float*)(ws + 101187584);

  prep<<<dim3(25088), dim3(256), 0, stream>>>(x, Wq, Wk, Wv, Wo, xb,
                                              wqT, wkT, wvT, woT, sint, cost);
  gemm_qk<<<dim3(16, 16), dim3(512), 131072, stream>>>(xb, wqT, wkT, qb, kb, sint, cost);
  gemm8<1><<<dim3(16, 16), dim3(512), 98304, stream>>>(xb, wvT, vtb, nullptr);
  attn_k<<<dim3(256), dim3(512), 131072, stream>>>(qb, kb, vtb, ctxb);
  gemm8<2><<<dim3(16, 16), dim3(512), 98304, stream>>>(ctxb, woT, nullptr, out);
}

// Round 20
// 240.658 us; speedup vs baseline: 1.0119x; 1.0119x over previous
//
#include <hip/hip_runtime.h>
#include <cstdint>
#include <cstddef>

typedef _Float16 f16;
typedef _Float16 f16x8 __attribute__((ext_vector_type(8)));
typedef _Float16 f16x4 __attribute__((ext_vector_type(4)));
typedef float    f32x4 __attribute__((ext_vector_type(4)));
typedef float    f32x16 __attribute__((ext_vector_type(16)));
typedef int      i32x4 __attribute__((ext_vector_type(4)));

#define S_CTX 2048
#define NH 16
#define DH 128

#define BAR() asm volatile("s_barrier" ::: "memory")
#define VMW(n) asm volatile("s_waitcnt vmcnt(" #n ")" ::: "memory")
#define MF(a, b, c) __builtin_amdgcn_mfma_f32_16x16x32_f16((a), (b), (c), 0, 0, 0)
#define MF32(a, b, c) __builtin_amdgcn_mfma_f32_32x32x16_f16((a), (b), (c), 0, 0, 0)

__device__ __forceinline__ void gload16(const void* g, void* l) {
  __builtin_amdgcn_global_load_lds(
      (const __attribute__((address_space(1))) void*)g,
      (__attribute__((address_space(3))) void*)l, 16, 0, 0);
}

__device__ __forceinline__ int pk2(float a, float b) {
  auto hv = __builtin_amdgcn_cvt_pkrtz(a, b);
  return __builtin_bit_cast(int, hv);
}
// v_permlane32_swap_b32: vdst[32:63] <-> vsrc[0:31]
__device__ __forceinline__ void pl_swap(int& a, int& b) {
  asm volatile("v_permlane32_swap_b32 %0, %1" : "+v"(a), "+v"(b));
}

// ---------- prep: rope tables + x->f16 + 4x weight transpose, one dispatch ----------
__global__ void prep(const float* __restrict__ x,
                     const float* __restrict__ w0, const float* __restrict__ w1,
                     const float* __restrict__ w2, const float* __restrict__ w3,
                     f16* __restrict__ xb,
                     f16* __restrict__ o0, f16* __restrict__ o1,
                     f16* __restrict__ o2, f16* __restrict__ o3,
                     float* __restrict__ sint, float* __restrict__ cost) {
  const int bid = blockIdx.x, tid = threadIdx.x;
  if (bid < 512) {                       // rope tables: 2048*64
    int idx = bid * 256 + tid;
    int j = idx & 63, s = idx >> 6;
    float invf = __expf(-(float)(2 * j) * (1.0f / 128.0f) * 9.210340371976184f);
    float a = (float)s * invf;
    sint[idx] = sinf(a);
    cost[idx] = cosf(a);
  } else if (bid < 8704) {               // x fp32 -> fp16
    int i = ((bid - 512) * 256 + tid) * 4;
    float4 v = *(const float4*)(x + i);
    f16x4 o; o[0] = (f16)v.x; o[1] = (f16)v.y; o[2] = (f16)v.z; o[3] = (f16)v.w;
    *(f16x4*)(xb + i) = o;
  } else {                               // W[k][n] fp32 -> Wt[n][k] fp16
    int b2 = bid - 8704;
    int z = b2 >> 12, rem = b2 & 4095;
    int by = rem >> 6, bx = rem & 63;
    int tx = tid & 31, ty = tid >> 5;
    const float* in; f16* out;
    switch (z) {
      case 0: in = w0; out = o0; break;
      case 1: in = w1; out = o1; break;
      case 2: in = w2; out = o2; break;
      default: in = w3; out = o3; break;
    }
    __shared__ float tl[32][33];
    int xc = bx * 32 + tx, yc = by * 32 + ty;
#pragma unroll
    for (int r = 0; r < 32; r += 8)
      tl[ty + r][tx] = in[(size_t)(yc + r) * 2048 + xc];
    __syncthreads();
    int xo = by * 32 + tx, yo = bx * 32 + ty;
#pragma unroll
    for (int r = 0; r < 32; r += 8)
      out[(size_t)(yo + r) * 2048 + xo] = (f16)tl[tx][ty + r];
  }
}

// ---------- Q+K fused GEMM: 256^2, 8 waves, 128x64/wave, depth-3 ring (R17/R18 best) ----------
// Phase: reads(slot p) || stage h(p+3) -> VMW(8) -> BAR -> MFMA -> BAR.
// RAW: reads at phase p need h(p): proven by phase p-1's VMW(8). WAR: slot[p&3]
// re-staged at p+1; reads complete before own MFMA (lgkm dep) before trailing BAR.
// Tail: p60 stages h63; VMW 8/4/0/nop. Measured 73.3-73.8us, MfmaUtil ~41%,
// bank conflicts 0 — the plain-HIP 2-barrier structural ceiling (6 probes).
__global__ __launch_bounds__(512, 1)
void gemm_qk(const f16* __restrict__ A, const f16* __restrict__ wqT,
             const f16* __restrict__ wkT,
             f16* __restrict__ qb, f16* __restrict__ kb,
             const float* __restrict__ sint, const float* __restrict__ cost) {
  extern __shared__ __align__(16) char lds[];
  const int tid = threadIdx.x, lane = tid & 63;
  const int wvi = tid >> 6, wm = wvi >> 2, wn = wvi & 3;
  const int gcol = blockIdx.x * 256;
  const int proj = gcol >> 11;
  const int col0 = gcol & 2047;
  const int row0 = blockIdx.y * 256;
  const f16* Bt = proj ? wkT : wqT;

  const int ca0 = tid, ca1 = tid + 512;
  const int ra0 = ca0 >> 2, ra1 = ca1 >> 2;
  const int sa0 = (ca0 & 3) ^ ((ra0 >> 1) & 3);
  const int sa1 = (ca1 & 3) ^ ((ra1 >> 1) & 3);
  const f16* gA0 = A + (size_t)(row0 + ra0) * 2048 + sa0 * 8;
  const f16* gA1 = A + (size_t)(row0 + ra1) * 2048 + sa1 * 8;
  const f16* gB0 = Bt + (size_t)(col0 + ra0) * 2048 + sa0 * 8;
  const f16* gB1 = Bt + (size_t)(col0 + ra1) * 2048 + sa1 * 8;

  const int kslot = lane >> 4;
  int aoff[8], boff[4];
#pragma unroll
  for (int i = 0; i < 8; i++) {
    int row = wm * 128 + i * 16 + (lane & 15);
    aoff[i] = row * 64 + ((kslot ^ ((row >> 1) & 3)) << 4);
  }
#pragma unroll
  for (int j = 0; j < 4; j++) {
    int rb = (wn >> 1) * 128 + (wn & 1) * 32 + (j & 1) * 16 + (j >> 1) * 64 + (lane & 15);
    boff[j] = rb * 64 + ((kslot ^ ((rb >> 1) & 3)) << 4);
  }

  f32x4 acc[8][4] = {};

#define QKPH(SLOT, HS, SSLOT, DOSTAGE, WN) do {                                \
    const char* As_ = lds + (SLOT) * 32768;                                    \
    const char* Bs_ = As_ + 16384;                                             \
    f16x8 af[8], bf[4];                                                        \
    _Pragma("unroll") for (int i_ = 0; i_ < 8; i_++)                           \
      af[i_] = *(const f16x8*)(As_ + aoff[i_]);                                \
    _Pragma("unroll") for (int j_ = 0; j_ < 4; j_++)                           \
      bf[j_] = *(const f16x8*)(Bs_ + boff[j_]);                                \
    if (DOSTAGE) {                                                             \
      char* dA = lds + (SSLOT) * 32768;                                        \
      gload16(gA0 + (HS) * 32, dA + ca0 * 16);                                 \
      gload16(gA1 + (HS) * 32, dA + ca1 * 16);                                 \
      gload16(gB0 + (HS) * 32, dA + 16384 + ca0 * 16);                         \
      gload16(gB1 + (HS) * 32, dA + 16384 + ca1 * 16);                         \
    }                                                                          \
    asm volatile("s_waitcnt vmcnt(" #WN ")" ::: "memory");                     \
    BAR();                                                                     \
    __builtin_amdgcn_s_setprio(1);                                             \
    _Pragma("unroll") for (int i_ = 0; i_ < 8; i_++)                           \
      _Pragma("unroll") for (int j_ = 0; j_ < 4; j_++)                         \
        acc[i_][j_] = MF(af[i_], bf[j_], acc[i_][j_]);                         \
    __builtin_amdgcn_s_setprio(0);                                             \
    BAR();                                                                     \
  } while (0)

  // prologue: stage halves 0,1,2 (12 loads); VMW(8) proves h0
#pragma unroll
  for (int h = 0; h < 3; h++) {
    char* dA = lds + h * 32768;
    gload16(gA0 + h * 32, dA + ca0 * 16);
    gload16(gA1 + h * 32, dA + ca1 * 16);
    gload16(gB0 + h * 32, dA + 16384 + ca0 * 16);
    gload16(gB1 + h * 32, dA + 16384 + ca1 * 16);
  }
  VMW(8); BAR();

  for (int t = 0; t < 15; ++t) {
    const int p = 4 * t;
    QKPH(0, p + 3, 3, 1, 8);
    QKPH(1, p + 4, 0, 1, 8);
    QKPH(2, p + 5, 1, 1, 8);
    QKPH(3, p + 6, 2, 1, 8);
  }
  QKPH(0, 63, 3, 1, 8);   // p60: consume h60, stage h63; VMW(8) proves h61
  QKPH(1, 0, 0, 0, 4);    // p61: consume h61; VMW(4) proves h62
  QKPH(2, 0, 0, 0, 0);    // p62: consume h62; VMW(0) proves h63
  QKPH(3, 0, 0, 0, 63);   // p63: consume h63
#undef QKPH

  // RoPE epilogue
  const int b = row0 >> 11, sb = row0 & 2047;
  f16* dst = proj ? kb : qb;
  const int h = (col0 >> 7) + (wn >> 1);
#pragma unroll
  for (int i = 0; i < 8; i++)
#pragma unroll
    for (int jj = 0; jj < 2; jj++)
#pragma unroll
      for (int r = 0; r < 4; r++) {
        int s = sb + wm * 128 + i * 16 + (lane >> 4) * 4 + r;
        int d = (wn & 1) * 32 + jj * 16 + (lane & 15);
        float cv = cost[s * 64 + d], sv = sint[s * 64 + d];
        float x1 = acc[i][jj][r], x2 = acc[i][jj + 2][r];
        size_t base = ((size_t)(b * NH + h) * S_CTX + s) << 7;
        dst[base + d]      = (f16)(x1 * cv - x2 * sv);
        dst[base + d + 64] = (f16)(x2 * cv + x1 * sv);
      }
}

// ---------- 8-phase GEMM (R13-proven): tile 256x128; MODE 1 = V^T epi, 2 = f32 epi ----------
template<int MODE>
__global__ __launch_bounds__(512, 1)
void gemm8(const f16* __restrict__ A, const f16* __restrict__ Bt,
           f16* __restrict__ vtb, float* __restrict__ of) {
  extern __shared__ __align__(16) char lds[];
#define RING_A(e) (lds + (e) * 16384)
#define RING_B(e) (lds + 65536 + (e) * 8192)
  const int tid = threadIdx.x, lane = tid & 63;
  const int wvi = tid >> 6, wm = wvi >> 1, wn = wvi & 1;
  const int col0 = blockIdx.x * 128;
  const int row0 = blockIdx.y * 256;

  const int ca0 = tid, ca1 = tid + 512, cb0 = tid;
  const int rAs0 = ca0 >> 2, rAs1 = ca1 >> 2, rBs0 = cb0 >> 2;
  const int sA0 = (ca0 & 3) ^ ((rAs0 >> 1) & 3);
  const int sA1 = (ca1 & 3) ^ ((rAs1 >> 1) & 3);
  const int sB0 = (cb0 & 3) ^ ((rBs0 >> 1) & 3);
  const f16* gA0 = A + (size_t)(row0 + rAs0) * 2048 + sA0 * 8;
  const f16* gA1 = A + (size_t)(row0 + rAs1) * 2048 + sA1 * 8;
  const f16* gB0 = Bt + (size_t)(col0 + rBs0) * 2048 + sB0 * 8;

  const int kslot = lane >> 4;
  int aoff[4], boff[4];
#pragma unroll
  for (int i = 0; i < 4; i++) {
    int row = wm * 64 + i * 16 + (lane & 15);
    aoff[i] = row * 64 + ((kslot ^ ((row >> 1) & 3)) << 4);
  }
#pragma unroll
  for (int j = 0; j < 4; j++) {
    int rb = wn * 32 + (j & 1) * 16 + (j >> 1) * 64 + (lane & 15);
    boff[j] = rb * 64 + ((kslot ^ ((rb >> 1) & 3)) << 4);
  }

  f32x4 acc[4][4] = {};

#define PH8(SLOT, HS, DOSTAGE, WN) do {                                        \
    const char* As_ = RING_A(SLOT);                                            \
    const char* Bs_ = RING_B(SLOT);                                            \
    f16x8 af[4], bf[4];                                                        \
    _Pragma("unroll") for (int i_ = 0; i_ < 4; i_++)                           \
      af[i_] = *(const f16x8*)(As_ + aoff[i_]);                                \
    _Pragma("unroll") for (int j_ = 0; j_ < 4; j_++)                           \
      bf[j_] = *(const f16x8*)(Bs_ + boff[j_]);                                \
    if (DOSTAGE) {                                                             \
      gload16(gA0 + (HS) * 32, RING_A((HS) & 3) + ca0 * 16);                   \
      gload16(gA1 + (HS) * 32, RING_A((HS) & 3) + ca1 * 16);                   \
      gload16(gB0 + (HS) * 32, RING_B((HS) & 3) + cb0 * 16);                   \
    }                                                                          \
    asm volatile("s_waitcnt vmcnt(" #WN ")" ::: "memory");                     \
    BAR();                                                                     \
    __builtin_amdgcn_s_setprio(1);                                             \
    _Pragma("unroll") for (int i_ = 0; i_ < 4; i_++)                           \
      _Pragma("unroll") for (int j_ = 0; j_ < 4; j_++)                         \
        acc[i_][j_] = MF(af[i_], bf[j_], acc[i_][j_]);                         \
    __builtin_amdgcn_s_setprio(0);                                             \
    BAR();                                                                     \
  } while (0)

#pragma unroll
  for (int h = 0; h < 3; h++) {
    gload16(gA0 + h * 32, RING_A(h) + ca0 * 16);
    gload16(gA1 + h * 32, RING_A(h) + ca1 * 16);
    gload16(gB0 + h * 32, RING_B(h) + cb0 * 16);
  }
  VMW(6); BAR();

  for (int t = 0; t < 15; ++t) {
    const int p = t * 4;
    PH8(0, p + 3, 1, 6);
    PH8(1, p + 4, 1, 6);
    PH8(2, p + 5, 1, 6);
    PH8(3, p + 6, 1, 6);
  }
  PH8(0, 63, 1, 6);
  PH8(1, 0, 0, 3);
  PH8(2, 0, 0, 0);
  PH8(3, 0, 0, 63);
#undef PH8

  const int b = row0 >> 11, sbase = row0 & 2047;

  if (MODE == 2) {
#pragma unroll
    for (int i = 0; i < 4; i++)
#pragma unroll
      for (int j = 0; j < 4; j++)
#pragma unroll
        for (int r = 0; r < 4; r++) {
          int row = row0 + wm * 64 + i * 16 + (lane >> 4) * 4 + r;
          int col = col0 + wn * 32 + (j & 1) * 16 + (j >> 1) * 64 + (lane & 15);
          of[(size_t)row * 2048 + col] = acc[i][j][r];
        }
  } else {
    // V^T epilogue: [256 s][128 d] -> vtb[b,h,d,s] via LDS (f16x4 units, XOR swz)
    const int h = col0 >> 7;
    f16x4* ldsv = (f16x4*)lds;
#pragma unroll
    for (int i = 0; i < 4; i++)
#pragma unroll
      for (int j = 0; j < 4; j++) {
        f16x4 v;
#pragma unroll
        for (int r = 0; r < 4; r++) v[r] = (f16)acc[i][j][r];
        int su = wm * 16 + i * 4 + (lane >> 4);
        int d  = wn * 32 + (j & 1) * 16 + (j >> 1) * 64 + (lane & 15);
        ldsv[d * 64 + (su ^ ((d << 1) & 63))] = v;
      }
    __syncthreads();
#pragma unroll
    for (int it = 0; it < 8; ++it) {
      int o = it * 512 + tid;
      int d = o >> 5, c = o & 31;
      int xc = (d << 1) & 63;
      f16x4 lo = ldsv[d * 64 + ((2 * c) ^ xc)];
      f16x4 hi = ldsv[d * 64 + ((2 * c + 1) ^ xc)];
      f16x8 vv;
      vv[0] = lo[0]; vv[1] = lo[1]; vv[2] = lo[2]; vv[3] = lo[3];
      vv[4] = hi[0]; vv[5] = hi[1]; vv[6] = hi[2]; vv[7] = hi[3];
      *(f16x8*)&vtb[((size_t)(b * NH + h) * DH + d) * S_CTX + sbase + c * 8] = vv;
    }
  }
#undef RING_A
#undef RING_B
}

// ---------- flash attention v5 (R15-proven): DUAL-STREAM, two independent 4-wave halves ----------
__global__ __launch_bounds__(512, 1)
void attn_k(const f16* __restrict__ q, const f16* __restrict__ kk,
            const f16* __restrict__ vt, f16* __restrict__ ctx) {
  extern __shared__ __align__(16) char alds[];
  const int tid = threadIdx.x, lane = tid & 63;
  const int halfid = tid >> 8;            // 0 = half A, 1 = half B
  const int tid2 = tid & 255;
  const int wv2 = tid2 >> 6;              // wave within half, 0..3
  const int lh = lane >> 5, q31 = lane & 31;
  const int bid = blockIdx.x;
  const int bh = (bid & 7) + 8 * ((bid >> 3) & 3);
  const int idxQ = bid >> 5;              // 0..7
  const int b = bh >> 4, h = bh & 15;
  const size_t plane = (size_t)bh * (S_CTX * DH);
  const f16* Qp = q + plane;
  const f16* Kp = kk + plane;
  const f16* Vp = vt + plane;
  const float LOG2E = 1.4426950408889634f;

  char* myH = alds + halfid * 65536;      // this half's 64KB K/V region
  float* O_lds = (float*)(alds + 65536);  // merge buffer = half B's region (dead K/V)
  float* ml_lds = (float*)alds;           // merge m/l = half A's region start

#define STAGE(T, BUF) do {                                                      \
    const f16* Kt = Kp + (size_t)(T) * 64 * DH;                                 \
    const f16* Vt = Vp + (size_t)(T) * 64;                                      \
    char* kb_ = myH + (BUF) * 16384;                                            \
    char* vb_ = myH + 32768 + (BUF) * 16384;                                    \
    _Pragma("unroll") for (int j_ = 0; j_ < 4; j_++) {                          \
      int c = tid2 + j_ * 256; int rk = c >> 4;                                 \
      gload16(Kt + (size_t)rk * DH + (((c & 15) ^ (rk & 7)) * 8), kb_ + c * 16); \
    }                                                                           \
    _Pragma("unroll") for (int j_ = 0; j_ < 4; j_++) {                          \
      int c = tid2 + j_ * 256; int rv = c >> 3;                                 \
      gload16(Vt + (size_t)rv * S_CTX + (((c & 7) ^ (rv & 7)) * 8), vb_ + c * 16); \
    }                                                                           \
  } while (0)

  for (int p = 0; p < 2; ++p) {
    const int Qt = p ? (15 - idxQ) : idxQ;
    const int q0 = Qt * 128;
    const int NTh = Qt + 1;               // iters per half (NT = 2Qt+2 split even/odd)

    // Q fragments (B-operand): lane holds Q[q0+wv2*32+q31][d = 16s + 8*lh + e]
    f16x8 qf[8];
    {
      const f16* qq = Qp + (size_t)(q0 + wv2 * 32 + q31) * DH + lh * 8;
#pragma unroll
      for (int s = 0; s < 8; s++) {
        qf[s] = *(const f16x8*)(qq + s * 16);
#pragma unroll
        for (int e = 0; e < 8; e++) qf[s][e] = (f16)((float)qf[s][e] * LOG2E);
      }
    }
    float m_ = -3e38f, l_ = 0.f;
    f32x16 o[4] = {};

    STAGE(halfid, 0);
    VMW(0); BAR();

    int cur = 0;
    for (int i = 0; i < NTh; i++) {
      const int t = 2 * i + halfid;
      if (i + 1 < NTh) STAGE(2 * (i + 1) + halfid, cur ^ 1);
      const f16* Ksc = (const f16*)(myH + cur * 16384);
      const f16* Vsc = (const f16*)(myH + 32768 + cur * 16384);

      // S^T = K Q (log2 units)
      f32x16 st0 = {}, st1 = {};
      __builtin_amdgcn_s_setprio(1);
#pragma unroll
      for (int s = 0; s < 8; s++) {
        const int r0 = q31, r1 = 32 + q31;
        f16x8 kf0 = *(const f16x8*)&Ksc[r0 * 128 + (((2 * s + lh) ^ (r0 & 7)) << 3)];
        f16x8 kf1 = *(const f16x8*)&Ksc[r1 * 128 + (((2 * s + lh) ^ (r1 & 7)) << 3)];
        st0 = MF32(kf0, qf[s], st0);
        st1 = MF32(kf1, qf[s], st1);
      }
      __builtin_amdgcn_s_setprio(0);

      // causal mask (diagonal band: t in {2Qt, 2Qt+1})
      if (t >= 2 * Qt) {
        const int qg = q0 + wv2 * 32 + q31;
#pragma unroll
        for (int r = 0; r < 16; r++) {
          int kvb = t * 64 + (r & 3) + 8 * (r >> 2) + 4 * lh;
          if (kvb > qg) st0[r] = -3e38f;
          if (kvb + 32 > qg) st1[r] = -3e38f;
        }
      }
      // row max: in-lane + partner half-lane
      float mx = st0[0];
#pragma unroll
      for (int r = 1; r < 16; r++) mx = fmaxf(mx, st0[r]);
#pragma unroll
      for (int r = 0; r < 16; r++) mx = fmaxf(mx, st1[r]);
      mx = fmaxf(mx, __shfl_xor(mx, 32));
      if (__any(mx > m_ + 8.0f)) {
        float nm = fmaxf(m_, mx);
        float al = __builtin_amdgcn_exp2f(m_ - nm);
        m_ = nm; l_ *= al;
#pragma unroll
        for (int r = 0; r < 16; r++) {
          float alr = __shfl(al, (r & 3) + 8 * (r >> 2) + 4 * lh);
#pragma unroll
          for (int j = 0; j < 4; j++) o[j][r] *= alr;
        }
      }
      float s_ = 0.f;
#pragma unroll
      for (int r = 0; r < 16; r++) { st0[r] = __builtin_amdgcn_exp2f(st0[r] - m_); s_ += st0[r]; }
#pragma unroll
      for (int r = 0; r < 16; r++) { st1[r] = __builtin_amdgcn_exp2f(st1[r] - m_); s_ += st1[r]; }
      s_ += __shfl_xor(s_, 32);
      l_ += s_;

      // pack P -> A-frags (16 cvt_pk + 8 permlane32_swap)
      f16x8 pa[4];
      {
        int w0 = pk2(st0[0], st0[1]),   w1 = pk2(st0[2], st0[3]);
        int w2 = pk2(st0[4], st0[5]),   w3 = pk2(st0[6], st0[7]);
        int w4 = pk2(st0[8], st0[9]),   w5 = pk2(st0[10], st0[11]);
        int w6 = pk2(st0[12], st0[13]), w7 = pk2(st0[14], st0[15]);
        pl_swap(w0, w2); pl_swap(w1, w3); pl_swap(w4, w6); pl_swap(w5, w7);
        i32x4 a = {w0, w1, w2, w3}; pa[0] = __builtin_bit_cast(f16x8, a);
        i32x4 bb = {w4, w5, w6, w7}; pa[1] = __builtin_bit_cast(f16x8, bb);
      }
      {
        int w0 = pk2(st1[0], st1[1]),   w1 = pk2(st1[2], st1[3]);
        int w2 = pk2(st1[4], st1[5]),   w3 = pk2(st1[6], st1[7]);
        int w4 = pk2(st1[8], st1[9]),   w5 = pk2(st1[10], st1[11]);
        int w6 = pk2(st1[12], st1[13]), w7 = pk2(st1[14], st1[15]);
        pl_swap(w0, w2); pl_swap(w1, w3); pl_swap(w4, w6); pl_swap(w5, w7);
        i32x4 a = {w0, w1, w2, w3}; pa[2] = __builtin_bit_cast(f16x8, a);
        i32x4 bb = {w4, w5, w6, w7}; pa[3] = __builtin_bit_cast(f16x8, bb);
      }

      // O += P V
      __builtin_amdgcn_s_setprio(1);
#pragma unroll
      for (int j = 0; j < 4; j++) {
        const int rv = 32 * j + q31;
#pragma unroll
        for (int s2 = 0; s2 < 4; s2++) {
          f16x8 vf = *(const f16x8*)&Vsc[rv * 64 + (((2 * s2 + lh) ^ (rv & 7)) << 3)];
          o[j] = MF32(pa[s2], vf, o[j]);
        }
      }
      __builtin_amdgcn_s_setprio(0);

      VMW(0); BAR();
      cur ^= 1;
    }

    // ---- merge: B spills, A combines + writes ctx ----
    if (halfid) {
      ml_lds[(wv2 * 32 + q31) * 2]     = m_;
      ml_lds[(wv2 * 32 + q31) * 2 + 1] = l_;
#pragma unroll
      for (int r = 0; r < 16; r++) {
        int crow = (r & 3) + 8 * (r >> 2) + 4 * lh;
#pragma unroll
        for (int j = 0; j < 4; j++)
          O_lds[(wv2 * 32 + crow) * 128 + 32 * j + q31] = o[j][r];
      }
    }
    BAR();
    if (!halfid) {
      float mB = ml_lds[(wv2 * 32 + q31) * 2];
      float lB = ml_lds[(wv2 * 32 + q31) * 2 + 1];
      float m = fmaxf(m_, mB);
      float aA = __builtin_amdgcn_exp2f(m_ - m);
      float aB = __builtin_amdgcn_exp2f(mB - m);
      float lfin = l_ * aA + lB * aB;
      float inv = 1.0f / lfin;
#pragma unroll
      for (int r = 0; r < 16; r++) {
        int crow = (r & 3) + 8 * (r >> 2) + 4 * lh;
        float aAr = __shfl(aA, crow);
        float aBr = __shfl(aB, crow);
        float invr = __shfl(inv, crow);
        int qg = q0 + wv2 * 32 + crow;
#pragma unroll
        for (int j = 0; j < 4; j++) {
          float ov = o[j][r] * aAr + O_lds[(wv2 * 32 + crow) * 128 + 32 * j + q31] * aBr;
          ctx[((size_t)(b * S_CTX + qg) * 2048) + h * 128 + 32 * j + q31] = (f16)(ov * invr);
        }
      }
    }
    BAR();   // O_lds / ml_lds regions reused as K/V next tile
  }
#undef STAGE
}

extern "C" void kernel_launch(void* const* d_in, const int* in_sizes, int n_in,
                              void* d_out, int out_size, void* d_ws, size_t ws_size,
                              hipStream_t stream) {
  (void)in_sizes; (void)n_in; (void)out_size; (void)ws_size;
  const float* x  = (const float*)d_in[0];
  const float* Wq = (const float*)d_in[1];
  const float* Wk = (const float*)d_in[2];
  const float* Wv = (const float*)d_in[3];
  const float* Wo = (const float*)d_in[4];
  float* out = (float*)d_out;
  char* ws = (char*)d_ws;

  f16*   xb   = (f16*)(ws);                    // x fp16 [4096][2048]
  f16*   ctxb = (f16*)(ws);                    // reuse (xb dead after QKV)
  f16*   wqT  = (f16*)(ws + 16777216);         // [n][k] fp16, 8 MB each
  f16*   wkT  = (f16*)(ws + 25165824);
  f16*   wvT  = (f16*)(ws + 33554432);
  f16*   woT  = (f16*)(ws + 41943040);
  f16*   qb   = (f16*)(ws + 50331648);         // [b,h,s,d] fp16 (rope applied)
  f16*   kb   = (f16*)(ws + 67108864);
  f16*   vtb  = (f16*)(ws + 83886080);         // [b,h,d,s] fp16
  float* sint = (float*)(ws + 100663296);      // [2048][64]
  float* cost = (float*)(ws + 101187584);

  prep<<<dim3(25088), dim3(256), 0, stream>>>(x, Wq, Wk, Wv, Wo, xb,
                                              wqT, wkT, wvT, woT, sint, cost);
  gemm_qk<<<dim3(16, 16), dim3(512), 131072, stream>>>(xb, wqT, wkT, qb, kb, sint, cost);
  gemm8<1><<<dim3(16, 16), dim3(512), 98304, stream>>>(xb, wvT, vtb, nullptr);
  attn_k<<<dim3(256), dim3(512), 131072, stream>>>(qb, kb, vtb, ctxb);
  gemm8<2><<<dim3(16, 16), dim3(512), 98304, stream>>>(ctxb, woT, nullptr, out);
}